// Round 14
// baseline (347.691 us; speedup 1.0000x reference)
//
#include <hip/hip_runtime.h>
#include <hip/hip_bf16.h>

#define DIM 192
#define HEADS 6
#define QKV_N 576
#define HIDDEN 768
#define M_ROWS 65536

typedef unsigned short ushortT;
typedef __attribute__((ext_vector_type(8))) short short8v;
typedef __attribute__((ext_vector_type(4))) float f32x4;
typedef __attribute__((ext_vector_type(4))) unsigned int u32x4;

// 1/sqrt(32) * log2(e) folded into Q columns at QKV epilogue
#define QSCALE_L2E 0.2550348649f
#define LOG2E 1.4426950408889634f

__device__ __forceinline__ float bf2f(ushortT u) {
    union { unsigned int i; float f; } c; c.i = ((unsigned int)u) << 16; return c.f;
}
__device__ __forceinline__ ushortT f2bf(float f) {
    union { float f; unsigned int i; } c; c.f = f;
    unsigned int i = c.i;
    return (ushortT)((i + 0x7fffu + ((i >> 16) & 1u)) >> 16);
}
__device__ __forceinline__ float fast_gelu(float v) {
    // x * sigmoid(1.5957691*(x + 0.044715 x^3)); exp2 domain (proven r4)
    float x3 = v * v * v;
    float z = fmaf(x3, -0.1029537917f, v * -2.302205077f);
    float e = exp2f(z);
    return v * __builtin_amdgcn_rcpf(1.0f + e);
}

#define GLOBAL_LOAD_LDS16(gp, lp) \
    __builtin_amdgcn_global_load_lds((const __attribute__((address_space(1))) void*)(gp), \
                                     (__attribute__((address_space(3))) void*)(lp), 16, 0, 0)

// ---------------- small shared MLP helper -------------------------------------------
__device__ __forceinline__ void ln_relu_mm12(const float* in, const float* g, const float* b,
                                             const float* w, const float* bb, float* out, int nout) {
    float m = 0.f;
#pragma unroll
    for (int j = 0; j < 12; ++j) m += in[j];
    m *= (1.0f / 12.0f);
    float v = 0.f;
#pragma unroll
    for (int j = 0; j < 12; ++j) { float d = in[j] - m; v += d * d; }
    v *= (1.0f / 12.0f);
    float r = rsqrtf(v + 1e-5f);
    float t[12];
#pragma unroll
    for (int j = 0; j < 12; ++j) t[j] = fmaxf((in[j] - m) * r * g[j] + b[j], 0.0f);
    for (int j2 = 0; j2 < nout; ++j2) {
        float s = bb[j2];
#pragma unroll
        for (int j = 0; j < 12; ++j) s = fmaf(t[j], w[j * nout + j2], s);
        out[j2] = s;
    }
}

// ---------------- prep + LN1 merged (independent work, one dispatch) -----------------
// blocks 0..431: 32x32 weight-transpose tiles (fc2 k-slot permuted);
// blocks 432..1967: BTf bias table (h*256+q per block);
// blocks 1968..18351: LN1 (x -> xn bf16), 4 rows per block.
__global__ __launch_bounds__(256) void prep_ln_kernel(
        const float* __restrict__ qkv_w, const float* __restrict__ proj_w,
        const float* __restrict__ fc1_w, const float* __restrict__ fc2_w,
        ushortT* __restrict__ qkv_wt, ushortT* __restrict__ proj_wt,
        ushortT* __restrict__ fc1_wt, ushortT* __restrict__ fc2_wt,
        const float* __restrict__ pw, const float* __restrict__ pb,
        const float* __restrict__ g1, const float* __restrict__ b1,
        const float* __restrict__ w1, const float* __restrict__ bb1,
        const float* __restrict__ g2, const float* __restrict__ b2,
        const float* __restrict__ w2, const float* __restrict__ bb2,
        const float* __restrict__ g3, const float* __restrict__ b3,
        const float* __restrict__ w3, const float* __restrict__ bb3,
        float* __restrict__ BTf,
        const float* __restrict__ x, const float* __restrict__ ln1g,
        const float* __restrict__ ln1b, ushortT* __restrict__ xn) {
    __shared__ float tile[32][33];
    int blk = blockIdx.x;
    int t = threadIdx.x;
    if (blk >= 1968) {
        // ---- LN1 ----
        int lane = t & 63;
        size_t row = (size_t)(blk - 1968) * 4 + (t >> 6);
        const float* xr = x + row * DIM;
        float v0 = xr[lane], v1 = xr[lane + 64], v2 = xr[lane + 128];
        float s = v0 + v1 + v2;
        float ss = v0 * v0 + v1 * v1 + v2 * v2;
#pragma unroll
        for (int off = 32; off > 0; off >>= 1) {
            s += __shfl_xor(s, off);
            ss += __shfl_xor(ss, off);
        }
        float mean = s * (1.0f / DIM);
        float rstd = rsqrtf(ss * (1.0f / DIM) - mean * mean + 1e-5f);
        ushortT* o = xn + row * DIM;
        o[lane]       = f2bf((v0 - mean) * rstd * ln1g[lane]       + ln1b[lane]);
        o[lane + 64]  = f2bf((v1 - mean) * rstd * ln1g[lane + 64]  + ln1b[lane + 64]);
        o[lane + 128] = f2bf((v2 - mean) * rstd * ln1g[lane + 128] + ln1b[lane + 128]);
    } else if (blk < 432) {
        const float* W; ushortT* Wt; int K, N, bx, by; bool perm = false;
        if (blk < 108)      { W = qkv_w;  Wt = qkv_wt;  K = 192; N = 576; bx = blk % 18;        by = blk / 18; }
        else if (blk < 144) { int r = blk - 108; W = proj_w; Wt = proj_wt; K = 192; N = 192; bx = r % 6;  by = r / 6; }
        else if (blk < 288) { int r = blk - 144; W = fc1_w;  Wt = fc1_wt;  K = 192; N = 768; bx = r % 24; by = r / 24; }
        else                { int r = blk - 288; W = fc2_w;  Wt = fc2_wt;  K = 768; N = 192; bx = r % 6;  by = r / 6; perm = true; }
        int tx = t & 31, ty = t >> 5;
        int bX = bx * 32, bY = by * 32;
#pragma unroll
        for (int i = 0; i < 32; i += 8)
            tile[ty + i][tx] = W[(size_t)(bY + ty + i) * N + bX + tx];
        __syncthreads();
        // k-col within 32-group; fc2 gets pk-permutation: k -> 2*(k&15) + (k>>4)
        int kcol = perm ? (((tx & 15) << 1) | (tx >> 4)) : tx;
#pragma unroll
        for (int i = 0; i < 32; i += 8)
            Wt[(size_t)(bX + ty + i) * K + bY + kcol] = f2bf(tile[tx][ty + i]);
    } else {
        int blk2 = blk - 432;                 // h*256 + q
        int h = blk2 >> 8, q = blk2 & 255, kv = t;
        float di = (float)((q >> 4) - (kv >> 4));
        float dj = (float)((q & 15) - (kv & 15));
        float a[12], hh[12];
#pragma unroll
        for (int j = 0; j < 12; ++j) a[j] = di * pw[j] + dj * pw[12 + j] + pb[j];
        ln_relu_mm12(a, g1, b1, w1, bb1, hh, 12);
        ln_relu_mm12(hh, g2, b2, w2, bb2, a, 12);
        // last layer: only head h
        float m = 0.f;
#pragma unroll
        for (int j = 0; j < 12; ++j) m += a[j];
        m *= (1.0f / 12.0f);
        float v = 0.f;
#pragma unroll
        for (int j = 0; j < 12; ++j) { float d = a[j] - m; v += d * d; }
        v *= (1.0f / 12.0f);
        float r = rsqrtf(v + 1e-5f);
        float s = bb3[h];
#pragma unroll
        for (int j = 0; j < 12; ++j)
            s = fmaf(fmaxf((a[j] - m) * r * g3[j] + b3[j], 0.0f), w3[j * 6 + h], s);
        // MFMA-fragment layout: seg = (h*8+kc)*32 + wid*8 + mf*2 + cf ; [lane][r]
        int wid = q >> 6, mf = (q >> 4) & 3, l4 = (q >> 2) & 3, rr = q & 3;
        int kc = kv >> 5, cc = kv & 31;
        int cf = (cc >> 4) & 1, l15 = cc & 15;
        int lane = l4 * 16 + l15;
        size_t off = ((size_t)((h * 8 + kc) * 32 + wid * 8 + mf * 2 + cf)) * 256 + lane * 4 + rr;
        BTf[off] = s * LOG2E;
    }
}

// ---------------- MFMA GEMM, double-buffered LDS + counted vmcnt ---------------------
// BM=128, BN=64, BK=64; 4 waves (2x2); XOR chunk-swizzled LDS; 1D grid, A-major
// logical order + bijective XCD-chunk swizzle (grid%8==0). KK = compile-time K.
// MODE 0: bf16 out, q-cols (<192) scaled by QSCALE_L2E ; 2: f32 out = resid + v
template <int MODE, int NY, int KK>
__global__ __launch_bounds__(256) void mfma_gemm(const ushortT* __restrict__ A,
                                                 const ushortT* __restrict__ Wt,
                                                 const float* __restrict__ bias,
                                                 const float* __restrict__ resid,
                                                 void* __restrict__ outp,
                                                 int N) {
    __shared__ ushortT As[2][128 * 64];
    __shared__ ushortT Bs[2][64 * 64];
    const int NT = KK / 64;
    int tid = threadIdx.x;
    int lane = tid & 63, wid = tid >> 6;
    int l15 = lane & 15, l4 = lane >> 4;
    int wr = wid >> 1, wc = wid & 1;
    int p = blockIdx.x;
    int cpx = gridDim.x >> 3;
    int logical = (p & 7) * cpx + (p >> 3);
    int bx = logical / NY;
    int by = logical - bx * NY;
    int bm = bx * 128, bn = by * 64;

    f32x4 acc[4][2];
#pragma unroll
    for (int mf = 0; mf < 4; ++mf)
#pragma unroll
        for (int nf = 0; nf < 2; ++nf)
#pragma unroll
            for (int r = 0; r < 4; ++r) acc[mf][nf][r] = 0.f;

    int srow = tid >> 3;
    int schunk = (tid & 7) ^ (srow & 7);
    const ushortT* agp = A + (size_t)(bm + srow) * KK + schunk * 8;
    const ushortT* bgp = Wt + (size_t)(bn + srow) * KK + schunk * 8;

    auto STAGE = [&](int buf, int t) {
        int k0 = t * 64;
#pragma unroll
        for (int i = 0; i < 4; ++i)
            GLOBAL_LOAD_LDS16(agp + (size_t)i * 32 * KK + k0, &As[buf][i * 2048 + wid * 512]);
#pragma unroll
        for (int i = 0; i < 2; ++i)
            GLOBAL_LOAD_LDS16(bgp + (size_t)i * 32 * KK + k0, &Bs[buf][i * 2048 + wid * 512]);
    };

    STAGE(0, 0);
    for (int t = 0; t < NT; ++t) {
        int cur = t & 1;
        if (t + 1 < NT) {
            STAGE(cur ^ 1, t + 1);
            asm volatile("s_waitcnt vmcnt(6)" ::: "memory");
        } else {
            asm volatile("s_waitcnt vmcnt(0)" ::: "memory");
        }
        __builtin_amdgcn_s_barrier();
        const ushortT* Asc = As[cur];
        const ushortT* Bsc = Bs[cur];
#pragma unroll
        for (int ks = 0; ks < 2; ++ks) {
            short8v af[4], bf[2];
#pragma unroll
            for (int mf = 0; mf < 4; ++mf) {
                int row = wr * 64 + mf * 16 + l15;
                af[mf] = *(const short8v*)&Asc[row * 64 + (((ks * 4 + l4) ^ (l15 & 7)) << 3)];
            }
#pragma unroll
            for (int nf = 0; nf < 2; ++nf) {
                int row = wc * 32 + nf * 16 + l15;
                bf[nf] = *(const short8v*)&Bsc[row * 64 + (((ks * 4 + l4) ^ (l15 & 7)) << 3)];
            }
#pragma unroll
            for (int mf = 0; mf < 4; ++mf)
#pragma unroll
                for (int nf = 0; nf < 2; ++nf)
                    acc[mf][nf] = __builtin_amdgcn_mfma_f32_16x16x32_bf16(af[mf], bf[nf], acc[mf][nf], 0, 0, 0);
        }
        __builtin_amdgcn_s_barrier();
    }
#pragma unroll
    for (int mf = 0; mf < 4; ++mf) {
        size_t row = (size_t)bm + wr * 64 + mf * 16 + l4 * 4;
#pragma unroll
        for (int nf = 0; nf < 2; ++nf) {
            int col = bn + wc * 32 + nf * 16 + l15;
            float bv = bias[col];
#pragma unroll
            for (int r = 0; r < 4; ++r) {
                size_t off = (row + r) * (size_t)N + col;
                float v = acc[mf][nf][r] + bv;
                if (MODE == 0) {
                    if (col < 192) v *= QSCALE_L2E;
                    ((ushortT*)outp)[off] = f2bf(v);
                } else {
                    ((float*)outp)[off] = resid[off] + v;
                }
            }
        }
    }
}

// ---------------- fused MLP v5: LN2 + fc1 + GELU + fc2 + residual --------------------
// 128 rows/block (512 blocks = ONE occupancy pass at 2 blocks/CU), 4 waves, each wave
// owns TWO 16-row tiles. A-operand in registers (MFMA A-frag layout). Proven r10 v2
// sync structure (Bs1 dbuf + Bs2 single + counted vmcnt, 3 barriers/chunk) with 2x
// MFMA per barrier; each Bs1 fragment read feeds both halves. Yl (wave-private) is
// time-shared between halves (same-wave DS ordering keeps pack(h1) after reads(h0)).
__global__ __launch_bounds__(256, 2) void mlp_kernel(float* out,
                                                     const ushortT* __restrict__ fc1t,
                                                     const ushortT* __restrict__ fc2t,
                                                     const float* __restrict__ fc1b,
                                                     const float* __restrict__ fc2b,
                                                     const float* __restrict__ g,
                                                     const float* __restrict__ b) {
    __shared__ ushortT Bs1[2][64 * 192];      // 48K dbuf
    __shared__ ushortT Bs2[192 * 64];         // 24K
    __shared__ unsigned int Yl[4][16 * 32];   // 8K  -> 80K total, 2 blocks/CU
    int tid = threadIdx.x, lane = tid & 63, wid = tid >> 6;
    int l15 = lane & 15, l4 = lane >> 4;
    size_t bm = (size_t)blockIdx.x * 128;

    // staging source offsets (pre-swizzled global source, linear LDS dest)
    int aoff1[6], aoff2[6];
#pragma unroll
    for (int i = 0; i < 6; ++i) {
        int u = tid + i * 256;
        int r1 = u / 24, rem = u - r1 * 24;   // fc1: 64 rows x 24 granules(16B)
        int kt = rem >> 3, w = rem & 7;
        aoff1[i] = r1 * 192 + kt * 64 + ((w ^ (r1 & 7)) << 3);
        int r2 = u >> 3, wp2 = u & 7;         // fc2: 192 rows x 8 granules(16B)
        aoff2[i] = r2 * 768 + ((wp2 ^ (r2 & 7)) << 3);
    }
    auto STAGE_B1 = [&](int buf, int hc) {
#pragma unroll
        for (int i = 0; i < 6; ++i)
            GLOBAL_LOAD_LDS16(fc1t + hc * 12288 + aoff1[i], &Bs1[buf][(tid + i * 256) * 8]);
    };
    auto STAGE_B2 = [&](int hc) {
#pragma unroll
        for (int i = 0; i < 6; ++i)
            GLOBAL_LOAD_LDS16(fc2t + hc * 64 + aoff2[i], &Bs2[(tid + i * 256) * 8]);
    };

    STAGE_B1(0, 0);   // chunk 0 in flight under the LN prologue

    // ---- LN2 prologue directly into A-fragments (registers), both halves ----
    short8v af[2][6];
#pragma unroll
    for (int hh = 0; hh < 2; ++hh) {
        int row = wid * 32 + hh * 16 + l15;
        const float* xr = out + (bm + row) * 192;
        float v[6][8];
        float s = 0.f, ss = 0.f;
#pragma unroll
        for (int f = 0; f < 6; ++f) {
            int base = (f >> 1) * 64 + (f & 1) * 32 + l4 * 8;
            f32x4 a0 = *(const f32x4*)(xr + base);
            f32x4 a1 = *(const f32x4*)(xr + base + 4);
#pragma unroll
            for (int j = 0; j < 4; ++j) {
                v[f][j] = a0[j]; v[f][4 + j] = a1[j];
                s += a0[j] + a1[j];
                ss += a0[j] * a0[j] + a1[j] * a1[j];
            }
        }
        s += __shfl_xor(s, 16); ss += __shfl_xor(ss, 16);
        s += __shfl_xor(s, 32); ss += __shfl_xor(ss, 32);
        float mean = s * (1.0f / 192.0f);
        float rstd = rsqrtf(ss * (1.0f / 192.0f) - mean * mean + 1e-5f);
#pragma unroll
        for (int f = 0; f < 6; ++f) {
            int base = (f >> 1) * 64 + (f & 1) * 32 + l4 * 8;
#pragma unroll
            for (int j = 0; j < 8; ++j)
                af[hh][f][j] = (short)f2bf((v[f][j] - mean) * rstd * g[base + j] + b[base + j]);
        }
    }

    f32x4 accO[2][12];
#pragma unroll
    for (int hh = 0; hh < 2; ++hh)
#pragma unroll
        for (int nf = 0; nf < 12; ++nf)
#pragma unroll
            for (int r = 0; r < 4; ++r) accO[hh][nf][r] = 0.f;

    for (int hc = 0; hc < 12; ++hc) {
        int cur = hc & 1;
        if (hc < 11) STAGE_B1(cur ^ 1, hc + 1);
        STAGE_B2(hc);
        if (hc < 11) asm volatile("s_waitcnt vmcnt(12)" ::: "memory");  // B1(cur) landed
        else         asm volatile("s_waitcnt vmcnt(6)"  ::: "memory");
        __builtin_amdgcn_s_barrier();
        // GEMM1 both halves: one Bs1 fragment read feeds two MFMAs
        f32x4 ya0[4], ya1[4];
#pragma unroll
        for (int n = 0; n < 4; ++n) {
            float bv = fc1b[hc * 64 + n * 16 + l15];
            ya0[n][0] = bv; ya0[n][1] = bv; ya0[n][2] = bv; ya0[n][3] = bv;
            ya1[n][0] = bv; ya1[n][1] = bv; ya1[n][2] = bv; ya1[n][3] = bv;
        }
        __builtin_amdgcn_s_setprio(1);
#pragma unroll
        for (int kt = 0; kt < 3; ++kt)
#pragma unroll
            for (int ks = 0; ks < 2; ++ks) {
                int wp = ((ks * 4 + l4) ^ (l15 & 7)) << 3;
#pragma unroll
                for (int n = 0; n < 4; ++n) {
                    short8v bf = *(const short8v*)&Bs1[cur][(n * 16 + l15) * 192 + kt * 64 + wp];
                    ya0[n] = __builtin_amdgcn_mfma_f32_16x16x32_bf16(af[0][kt * 2 + ks], bf, ya0[n], 0, 0, 0);
                    ya1[n] = __builtin_amdgcn_mfma_f32_16x16x32_bf16(af[1][kt * 2 + ks], bf, ya1[n], 0, 0, 0);
                }
            }
        __builtin_amdgcn_s_setprio(0);
        // GELU + pack h0 -> Yl (rows 4*l4+r), XOR chunk swizzle (key row&7)
#pragma unroll
        for (int r = 0; r < 4; ++r) {
            int row = 4 * l4 + r;
            int key = row & 7;
#pragma unroll
            for (int gg = 0; gg < 2; ++gg) {
                float y0 = fast_gelu(ya0[gg * 2 + 0][r]);
                float y1 = fast_gelu(ya0[gg * 2 + 1][r]);
                unsigned int pk;
                asm("v_cvt_pk_bf16_f32 %0, %1, %2" : "=v"(pk) : "v"(y0), "v"(y1));
                int ucol = gg * 16 + l15;
                int ch = (ucol >> 2) ^ key;
                Yl[wid][row * 32 + ch * 4 + (ucol & 3)] = pk;
            }
        }
        if (hc < 11) asm volatile("s_waitcnt vmcnt(6)" ::: "memory");   // B2(hc) landed
        else         asm volatile("s_waitcnt vmcnt(0)" ::: "memory");
        __builtin_amdgcn_s_barrier();
        // GEMM2 h0
        __builtin_amdgcn_s_setprio(1);
#pragma unroll
        for (int gg = 0; gg < 2; ++gg) {
            u32x4 pr = *(const u32x4*)&Yl[wid][l15 * 32 + (((gg * 4 + l4) ^ (l15 & 7)) << 2)];
            short8v pa = __builtin_bit_cast(short8v, pr);
#pragma unroll
            for (int nf = 0; nf < 12; ++nf) {
                short8v bf = *(const short8v*)&Bs2[(nf * 16 + l15) * 64 + (((gg * 4 + l4) ^ (l15 & 7)) << 3)];
                accO[0][nf] = __builtin_amdgcn_mfma_f32_16x16x32_bf16(pa, bf, accO[0][nf], 0, 0, 0);
            }
        }
        __builtin_amdgcn_s_setprio(0);
        // GELU + pack h1 -> Yl (same wave-private buffer; same-wave DS order keeps
        // these writes after GEMM2 h0's Yl reads)
#pragma unroll
        for (int r = 0; r < 4; ++r) {
            int row = 4 * l4 + r;
            int key = row & 7;
#pragma unroll
            for (int gg = 0; gg < 2; ++gg) {
                float y0 = fast_gelu(ya1[gg * 2 + 0][r]);
                float y1 = fast_gelu(ya1[gg * 2 + 1][r]);
                unsigned int pk;
                asm("v_cvt_pk_bf16_f32 %0, %1, %2" : "=v"(pk) : "v"(y0), "v"(y1));
                int ucol = gg * 16 + l15;
                int ch = (ucol >> 2) ^ key;
                Yl[wid][row * 32 + ch * 4 + (ucol & 3)] = pk;
            }
        }
        // GEMM2 h1
        __builtin_amdgcn_s_setprio(1);
#pragma unroll
        for (int gg = 0; gg < 2; ++gg) {
            u32x4 pr = *(const u32x4*)&Yl[wid][l15 * 32 + (((gg * 4 + l4) ^ (l15 & 7)) << 2)];
            short8v pa = __builtin_bit_cast(short8v, pr);
#pragma unroll
            for (int nf = 0; nf < 12; ++nf) {
                short8v bf = *(const short8v*)&Bs2[(nf * 16 + l15) * 64 + (((gg * 4 + l4) ^ (l15 & 7)) << 3)];
                accO[1][nf] = __builtin_amdgcn_mfma_f32_16x16x32_bf16(pa, bf, accO[1][nf], 0, 0, 0);
            }
        }
        __builtin_amdgcn_s_setprio(0);
        __builtin_amdgcn_s_barrier();   // Bs1[cur]/Bs2 free for restage next chunk
    }
    // epilogue: out += fc2 bias + acc (residual already in out), both halves
#pragma unroll
    for (int hh = 0; hh < 2; ++hh) {
        size_t row0 = bm + wid * 32 + hh * 16 + l4 * 4;
#pragma unroll
        for (int nf = 0; nf < 12; ++nf) {
            int col = nf * 16 + l15;
            float bv = fc2b[col];
#pragma unroll
            for (int r = 0; r < 4; ++r) {
                size_t off = (row0 + r) * 192 + col;
                out[off] = out[off] + bv + accO[hh][nf][r];
            }
        }
    }
}

// ---------------- MFMA flash attention (no-max softmax, per-mf interleave) -----------
// K-fragment prefetch (kfB) across chunks; per-mf s keeps VGPR < 128 so (256,4) holds.
__global__ __launch_bounds__(256, 4) void attn_mfma_kernel(const ushortT* __restrict__ qkv,
                                                           const float* __restrict__ BTf,
                                                           ushortT* __restrict__ O) {
    __shared__ ushortT Vt[32][264];
    __shared__ unsigned int Ps[4][64][20];
    int wh = blockIdx.x;
    int w = wh / 6, h = wh - w * 6;
    int wi = w >> 4, wj = w & 15;
    int tid = threadIdx.x, lane = tid & 63, wid = tid >> 6;
    int l15 = lane & 15, l4 = lane >> 4;

    {
        int t = tid;
        int pcol = (t & ~31) | (((t & 15) << 1) | ((t >> 4) & 1));
        size_t gr = (size_t)((wi * 16 + (t >> 4)) * 256 + wj * 16 + (t & 15));
        const ushortT* vp = qkv + gr * 576 + 384 + h * 32;
#pragma unroll
        for (int d0 = 0; d0 < 32; d0 += 8) {
            short8v u = *(const short8v*)(vp + d0);
#pragma unroll
            for (int j = 0; j < 8; ++j) Vt[d0 + j][pcol] = (ushortT)u[j];
        }
    }
    short8v qf[4];
    int qbase = wid * 64;
#pragma unroll
    for (int mf = 0; mf < 4; ++mf) {
        int q = qbase + mf * 16 + l15;
        size_t gr = (size_t)((wi * 16 + (q >> 4)) * 256 + wj * 16 + (q & 15));
        qf[mf] = *(const short8v*)(qkv + gr * 576 + h * 32 + l4 * 8);
    }
    __syncthreads();

    float l_run[4][4];
    f32x4 accO[4][2];
#pragma unroll
    for (int mf = 0; mf < 4; ++mf)
#pragma unroll
        for (int r = 0; r < 4; ++r) {
            l_run[mf][r] = 0.f;
            accO[mf][0][r] = 0.f;
            accO[mf][1][r] = 0.f;
        }
    const float* btb = BTf + ((size_t)(h * 8) * 32 + wid * 8) * 256 + lane * 4;

    auto load_kf = [&](int kc, short8v* kf) {
#pragma unroll
        for (int cf = 0; cf < 2; ++cf) {
            int kv = kc * 32 + cf * 16 + l15;
            size_t gr = (size_t)((wi * 16 + (kv >> 4)) * 256 + wj * 16 + (kv & 15));
            kf[cf] = *(const short8v*)(qkv + gr * 576 + 192 + h * 32 + l4 * 8);
        }
    };

    short8v kfA[2], kfB[2];
    load_kf(0, kfA);

    for (int kc = 0; kc < 8; ++kc) {
        if (kc < 7) load_kf(kc + 1, kfB);    // prefetch next chunk's K
        short8v vb[2];
#pragma unroll
        for (int nf = 0; nf < 2; ++nf)
            vb[nf] = *(const short8v*)&Vt[nf * 16 + l15][kc * 32 + l4 * 8];
#pragma unroll
        for (int mf = 0; mf < 4; ++mf) {
            f32x4 s0 = *(const f32x4*)(btb + (size_t)(kc * 32 + mf * 2 + 0) * 256);
            f32x4 s1 = *(const f32x4*)(btb + (size_t)(kc * 32 + mf * 2 + 1) * 256);
            __builtin_amdgcn_s_setprio(1);
            s0 = __builtin_amdgcn_mfma_f32_16x16x32_bf16(qf[mf], kfA[0], s0, 0, 0, 0);
            s1 = __builtin_amdgcn_mfma_f32_16x16x32_bf16(qf[mf], kfA[1], s1, 0, 0, 0);
            __builtin_amdgcn_s_setprio(0);
#pragma unroll
            for (int r = 0; r < 4; ++r) {
                float p0 = exp2f(s0[r]);
                float p1 = exp2f(s1[r]);
                l_run[mf][r] += p0 + p1;
                unsigned int pk;
                asm("v_cvt_pk_bf16_f32 %0, %1, %2" : "=v"(pk) : "v"(p0), "v"(p1));
                Ps[wid][mf * 16 + 4 * l4 + r][l15] = pk;
            }
            u32x4 pr = *(const u32x4*)&Ps[wid][mf * 16 + l15][l4 * 4];
            short8v pa = __builtin_bit_cast(short8v, pr);
            __builtin_amdgcn_s_setprio(1);
            accO[mf][0] = __builtin_amdgcn_mfma_f32_16x16x32_bf16(pa, vb[0], accO[mf][0], 0, 0, 0);
            accO[mf][1] = __builtin_amdgcn_mfma_f32_16x16x32_bf16(pa, vb[1], accO[mf][1], 0, 0, 0);
            __builtin_amdgcn_s_setprio(0);
        }
        kfA[0] = kfB[0]; kfA[1] = kfB[1];
    }
#pragma unroll
    for (int mf = 0; mf < 4; ++mf)
#pragma unroll
        for (int r = 0; r < 4; ++r) {
            float l = l_run[mf][r];
            l += __shfl_xor(l, 1);
            l += __shfl_xor(l, 2);
            l += __shfl_xor(l, 4);
            l += __shfl_xor(l, 8);
            l_run[mf][r] = 1.0f / l;
        }
#pragma unroll
    for (int mf = 0; mf < 4; ++mf) {
        int q0 = qbase + mf * 16 + 4 * l4;
#pragma unroll
        for (int r = 0; r < 4; ++r) {
            int q = q0 + r;
            size_t gr = (size_t)((wi * 16 + (q >> 4)) * 256 + wj * 16 + (q & 15));
            ushortT* op = O + gr * 192 + h * 32 + l15;
            float inv = l_run[mf][r];
            op[0]  = f2bf(accO[mf][0][r] * inv);
            op[16] = f2bf(accO[mf][1][r] * inv);
        }
    }
}

// ---------------- launch --------------------------------------------------------------
extern "C" void kernel_launch(void* const* d_in, const int* in_sizes, int n_in,
                              void* d_out, int out_size, void* d_ws, size_t ws_size,
                              hipStream_t stream) {
    const float* x        = (const float*)d_in[0];
    const float* gamma1   = (const float*)d_in[1];
    const float* beta1    = (const float*)d_in[2];
    const float* qkv_w    = (const float*)d_in[3];
    const float* qkv_b    = (const float*)d_in[4];
    const float* proj_w   = (const float*)d_in[5];
    const float* proj_b   = (const float*)d_in[6];
    const float* pos_proj_w = (const float*)d_in[7];
    const float* pos_proj_b = (const float*)d_in[8];
    const float* ln1_g    = (const float*)d_in[9];
    const float* ln1_b    = (const float*)d_in[10];
    const float* pos1_w   = (const float*)d_in[11];
    const float* pos1_b   = (const float*)d_in[12];
    const float* ln2_g    = (const float*)d_in[13];
    const float* ln2_b    = (const float*)d_in[14];
    const float* pos2_w   = (const float*)d_in[15];
    const float* pos2_b   = (const float*)d_in[16];
    const float* ln3_g    = (const float*)d_in[17];
    const float* ln3_b    = (const float*)d_in[18];
    const float* pos3_w   = (const float*)d_in[19];
    const float* pos3_b   = (const float*)d_in[20];
    const float* gamma2   = (const float*)d_in[21];
    const float* beta2    = (const float*)d_in[22];
    const float* fc1_w    = (const float*)d_in[23];
    const float* fc1_b    = (const float*)d_in[24];
    const float* fc2_w    = (const float*)d_in[25];
    const float* fc2_b    = (const float*)d_in[26];
    float* out = (float*)d_out;

    char* ws = (char*)d_ws;
    ushortT* qkv = (ushortT*)(ws + 0);               // 75.5MB
    ushortT* xn   = (ushortT*)(ws + 100663296);      // 25.2MB (xn -> Obuf)
    ushortT* Obuf = xn;
    ushortT* qkv_wt  = (ushortT*)(ws + 125829120);
    ushortT* proj_wt = (ushortT*)(ws + 126050304);
    ushortT* fc1_wt  = (ushortT*)(ws + 126124032);
    ushortT* fc2_wt  = (ushortT*)(ws + 126418944);
    float*   BTf     = (float*)(ws + 126713856);

    // 0. prep (transposes + bias table) + LN1, merged into one dispatch
    prep_ln_kernel<<<18352, 256, 0, stream>>>(
        qkv_w, proj_w, fc1_w, fc2_w, qkv_wt, proj_wt, fc1_wt, fc2_wt,
        pos_proj_w, pos_proj_b, ln1_g, ln1_b, pos1_w, pos1_b,
        ln2_g, ln2_b, pos2_w, pos2_b, ln3_g, ln3_b, pos3_w, pos3_b, BTf,
        x, gamma1, beta1, xn);
    // 1. QKV GEMM (q-cols pre-scaled)
    mfma_gemm<0, 9, 192><<<(M_ROWS / 128) * (QKV_N / 64), 256, 0, stream>>>(
        xn, qkv_wt, qkv_b, nullptr, qkv, QKV_N);
    // 2. attention -> Obuf (overwrites xn)
    attn_mfma_kernel<<<1536, 256, 0, stream>>>(qkv, BTf, Obuf);
    // 3. proj GEMM + residual -> out (f32)
    mfma_gemm<2, 3, 192><<<(M_ROWS / 128) * (DIM / 64), 256, 0, stream>>>(
        Obuf, proj_wt, proj_b, x, out, DIM);
    // 4. fused MLP v5: LN2 + fc1 + GELU + fc2 + residual, 128 rows/block, in-place
    mlp_kernel<<<M_ROWS / 128, 256, 0, stream>>>(
        out, fc1_wt, fc2_wt, fc1_b, fc2_b, gamma2, beta2);
}

// Round 15
// 196.340 us; speedup vs baseline: 1.7709x; 1.7709x over previous
//
#include <hip/hip_runtime.h>
#include <hip/hip_bf16.h>

#define DIM 192
#define HEADS 6
#define QKV_N 576
#define HIDDEN 768
#define M_ROWS 65536

typedef unsigned short ushortT;
typedef __attribute__((ext_vector_type(8))) short short8v;
typedef __attribute__((ext_vector_type(4))) float f32x4;
typedef __attribute__((ext_vector_type(4))) unsigned int u32x4;

// 1/sqrt(32) * log2(e) folded into Q columns at QKV epilogue
#define QSCALE_L2E 0.2550348649f
#define LOG2E 1.4426950408889634f

__device__ __forceinline__ float bf2f(ushortT u) {
    union { unsigned int i; float f; } c; c.i = ((unsigned int)u) << 16; return c.f;
}
__device__ __forceinline__ ushortT f2bf(float f) {
    union { float f; unsigned int i; } c; c.f = f;
    unsigned int i = c.i;
    return (ushortT)((i + 0x7fffu + ((i >> 16) & 1u)) >> 16);
}
__device__ __forceinline__ float fast_gelu(float v) {
    // x * sigmoid(1.5957691*(x + 0.044715 x^3)); exp2 domain (proven r4)
    float x3 = v * v * v;
    float z = fmaf(x3, -0.1029537917f, v * -2.302205077f);
    float e = exp2f(z);
    return v * __builtin_amdgcn_rcpf(1.0f + e);
}

#define GLOBAL_LOAD_LDS16(gp, lp) \
    __builtin_amdgcn_global_load_lds((const __attribute__((address_space(1))) void*)(gp), \
                                     (__attribute__((address_space(3))) void*)(lp), 16, 0, 0)

// ---------------- small shared MLP helper -------------------------------------------
__device__ __forceinline__ void ln_relu_mm12(const float* in, const float* g, const float* b,
                                             const float* w, const float* bb, float* out, int nout) {
    float m = 0.f;
#pragma unroll
    for (int j = 0; j < 12; ++j) m += in[j];
    m *= (1.0f / 12.0f);
    float v = 0.f;
#pragma unroll
    for (int j = 0; j < 12; ++j) { float d = in[j] - m; v += d * d; }
    v *= (1.0f / 12.0f);
    float r = rsqrtf(v + 1e-5f);
    float t[12];
#pragma unroll
    for (int j = 0; j < 12; ++j) t[j] = fmaxf((in[j] - m) * r * g[j] + b[j], 0.0f);
    for (int j2 = 0; j2 < nout; ++j2) {
        float s = bb[j2];
#pragma unroll
        for (int j = 0; j < 12; ++j) s = fmaf(t[j], w[j * nout + j2], s);
        out[j2] = s;
    }
}

// ---------------- prep + LN1 merged (independent work, one dispatch) -----------------
// blocks 0..431: 32x32 weight-transpose tiles (fc2 k-slot permuted);
// blocks 432..1967: BTf bias table (h*256+q per block);
// blocks 1968..18351: LN1 (x -> xn bf16), 4 rows per block.
__global__ __launch_bounds__(256) void prep_ln_kernel(
        const float* __restrict__ qkv_w, const float* __restrict__ proj_w,
        const float* __restrict__ fc1_w, const float* __restrict__ fc2_w,
        ushortT* __restrict__ qkv_wt, ushortT* __restrict__ proj_wt,
        ushortT* __restrict__ fc1_wt, ushortT* __restrict__ fc2_wt,
        const float* __restrict__ pw, const float* __restrict__ pb,
        const float* __restrict__ g1, const float* __restrict__ b1,
        const float* __restrict__ w1, const float* __restrict__ bb1,
        const float* __restrict__ g2, const float* __restrict__ b2,
        const float* __restrict__ w2, const float* __restrict__ bb2,
        const float* __restrict__ g3, const float* __restrict__ b3,
        const float* __restrict__ w3, const float* __restrict__ bb3,
        float* __restrict__ BTf,
        const float* __restrict__ x, const float* __restrict__ ln1g,
        const float* __restrict__ ln1b, ushortT* __restrict__ xn) {
    __shared__ float tile[32][33];
    int blk = blockIdx.x;
    int t = threadIdx.x;
    if (blk >= 1968) {
        // ---- LN1 ----
        int lane = t & 63;
        size_t row = (size_t)(blk - 1968) * 4 + (t >> 6);
        const float* xr = x + row * DIM;
        float v0 = xr[lane], v1 = xr[lane + 64], v2 = xr[lane + 128];
        float s = v0 + v1 + v2;
        float ss = v0 * v0 + v1 * v1 + v2 * v2;
#pragma unroll
        for (int off = 32; off > 0; off >>= 1) {
            s += __shfl_xor(s, off);
            ss += __shfl_xor(ss, off);
        }
        float mean = s * (1.0f / DIM);
        float rstd = rsqrtf(ss * (1.0f / DIM) - mean * mean + 1e-5f);
        ushortT* o = xn + row * DIM;
        o[lane]       = f2bf((v0 - mean) * rstd * ln1g[lane]       + ln1b[lane]);
        o[lane + 64]  = f2bf((v1 - mean) * rstd * ln1g[lane + 64]  + ln1b[lane + 64]);
        o[lane + 128] = f2bf((v2 - mean) * rstd * ln1g[lane + 128] + ln1b[lane + 128]);
    } else if (blk < 432) {
        const float* W; ushortT* Wt; int K, N, bx, by; bool perm = false;
        if (blk < 108)      { W = qkv_w;  Wt = qkv_wt;  K = 192; N = 576; bx = blk % 18;        by = blk / 18; }
        else if (blk < 144) { int r = blk - 108; W = proj_w; Wt = proj_wt; K = 192; N = 192; bx = r % 6;  by = r / 6; }
        else if (blk < 288) { int r = blk - 144; W = fc1_w;  Wt = fc1_wt;  K = 192; N = 768; bx = r % 24; by = r / 24; }
        else                { int r = blk - 288; W = fc2_w;  Wt = fc2_wt;  K = 768; N = 192; bx = r % 6;  by = r / 6; perm = true; }
        int tx = t & 31, ty = t >> 5;
        int bX = bx * 32, bY = by * 32;
#pragma unroll
        for (int i = 0; i < 32; i += 8)
            tile[ty + i][tx] = W[(size_t)(bY + ty + i) * N + bX + tx];
        __syncthreads();
        // k-col within 32-group; fc2 gets pk-permutation: k -> 2*(k&15) + (k>>4)
        int kcol = perm ? (((tx & 15) << 1) | (tx >> 4)) : tx;
#pragma unroll
        for (int i = 0; i < 32; i += 8)
            Wt[(size_t)(bX + ty + i) * K + bY + kcol] = f2bf(tile[tx][ty + i]);
    } else {
        int blk2 = blk - 432;                 // h*256 + q
        int h = blk2 >> 8, q = blk2 & 255, kv = t;
        float di = (float)((q >> 4) - (kv >> 4));
        float dj = (float)((q & 15) - (kv & 15));
        float a[12], hh[12];
#pragma unroll
        for (int j = 0; j < 12; ++j) a[j] = di * pw[j] + dj * pw[12 + j] + pb[j];
        ln_relu_mm12(a, g1, b1, w1, bb1, hh, 12);
        ln_relu_mm12(hh, g2, b2, w2, bb2, a, 12);
        // last layer: only head h
        float m = 0.f;
#pragma unroll
        for (int j = 0; j < 12; ++j) m += a[j];
        m *= (1.0f / 12.0f);
        float v = 0.f;
#pragma unroll
        for (int j = 0; j < 12; ++j) { float d = a[j] - m; v += d * d; }
        v *= (1.0f / 12.0f);
        float r = rsqrtf(v + 1e-5f);
        float s = bb3[h];
#pragma unroll
        for (int j = 0; j < 12; ++j)
            s = fmaf(fmaxf((a[j] - m) * r * g3[j] + b3[j], 0.0f), w3[j * 6 + h], s);
        // MFMA-fragment layout: seg = (h*8+kc)*32 + wid*8 + mf*2 + cf ; [lane][r]
        int wid = q >> 6, mf = (q >> 4) & 3, l4 = (q >> 2) & 3, rr = q & 3;
        int kc = kv >> 5, cc = kv & 31;
        int cf = (cc >> 4) & 1, l15 = cc & 15;
        int lane = l4 * 16 + l15;
        size_t off = ((size_t)((h * 8 + kc) * 32 + wid * 8 + mf * 2 + cf)) * 256 + lane * 4 + rr;
        BTf[off] = s * LOG2E;
    }
}

// ---------------- MFMA GEMM, double-buffered LDS + counted vmcnt ---------------------
// BM=128, BN=64, BK=64; 4 waves (2x2); XOR chunk-swizzled LDS; 1D grid, A-major
// logical order + bijective XCD-chunk swizzle (grid%8==0). KK = compile-time K.
// MODE 0: bf16 out, q-cols (<192) scaled by QSCALE_L2E ; 2: f32 out = resid + v
template <int MODE, int NY, int KK>
__global__ __launch_bounds__(256) void mfma_gemm(const ushortT* __restrict__ A,
                                                 const ushortT* __restrict__ Wt,
                                                 const float* __restrict__ bias,
                                                 const float* __restrict__ resid,
                                                 void* __restrict__ outp,
                                                 int N) {
    __shared__ ushortT As[2][128 * 64];
    __shared__ ushortT Bs[2][64 * 64];
    const int NT = KK / 64;
    int tid = threadIdx.x;
    int lane = tid & 63, wid = tid >> 6;
    int l15 = lane & 15, l4 = lane >> 4;
    int wr = wid >> 1, wc = wid & 1;
    int p = blockIdx.x;
    int cpx = gridDim.x >> 3;
    int logical = (p & 7) * cpx + (p >> 3);
    int bx = logical / NY;
    int by = logical - bx * NY;
    int bm = bx * 128, bn = by * 64;

    f32x4 acc[4][2];
#pragma unroll
    for (int mf = 0; mf < 4; ++mf)
#pragma unroll
        for (int nf = 0; nf < 2; ++nf)
#pragma unroll
            for (int r = 0; r < 4; ++r) acc[mf][nf][r] = 0.f;

    int srow = tid >> 3;
    int schunk = (tid & 7) ^ (srow & 7);
    const ushortT* agp = A + (size_t)(bm + srow) * KK + schunk * 8;
    const ushortT* bgp = Wt + (size_t)(bn + srow) * KK + schunk * 8;

    auto STAGE = [&](int buf, int t) {
        int k0 = t * 64;
#pragma unroll
        for (int i = 0; i < 4; ++i)
            GLOBAL_LOAD_LDS16(agp + (size_t)i * 32 * KK + k0, &As[buf][i * 2048 + wid * 512]);
#pragma unroll
        for (int i = 0; i < 2; ++i)
            GLOBAL_LOAD_LDS16(bgp + (size_t)i * 32 * KK + k0, &Bs[buf][i * 2048 + wid * 512]);
    };

    STAGE(0, 0);
    for (int t = 0; t < NT; ++t) {
        int cur = t & 1;
        if (t + 1 < NT) {
            STAGE(cur ^ 1, t + 1);
            asm volatile("s_waitcnt vmcnt(6)" ::: "memory");
        } else {
            asm volatile("s_waitcnt vmcnt(0)" ::: "memory");
        }
        __builtin_amdgcn_s_barrier();
        const ushortT* Asc = As[cur];
        const ushortT* Bsc = Bs[cur];
#pragma unroll
        for (int ks = 0; ks < 2; ++ks) {
            short8v af[4], bf[2];
#pragma unroll
            for (int mf = 0; mf < 4; ++mf) {
                int row = wr * 64 + mf * 16 + l15;
                af[mf] = *(const short8v*)&Asc[row * 64 + (((ks * 4 + l4) ^ (l15 & 7)) << 3)];
            }
#pragma unroll
            for (int nf = 0; nf < 2; ++nf) {
                int row = wc * 32 + nf * 16 + l15;
                bf[nf] = *(const short8v*)&Bsc[row * 64 + (((ks * 4 + l4) ^ (l15 & 7)) << 3)];
            }
#pragma unroll
            for (int mf = 0; mf < 4; ++mf)
#pragma unroll
                for (int nf = 0; nf < 2; ++nf)
                    acc[mf][nf] = __builtin_amdgcn_mfma_f32_16x16x32_bf16(af[mf], bf[nf], acc[mf][nf], 0, 0, 0);
        }
        __builtin_amdgcn_s_barrier();
    }
#pragma unroll
    for (int mf = 0; mf < 4; ++mf) {
        size_t row = (size_t)bm + wr * 64 + mf * 16 + l4 * 4;
#pragma unroll
        for (int nf = 0; nf < 2; ++nf) {
            int col = bn + wc * 32 + nf * 16 + l15;
            float bv = bias[col];
#pragma unroll
            for (int r = 0; r < 4; ++r) {
                size_t off = (row + r) * (size_t)N + col;
                float v = acc[mf][nf][r] + bv;
                if (MODE == 0) {
                    if (col < 192) v *= QSCALE_L2E;
                    ((ushortT*)outp)[off] = f2bf(v);
                } else {
                    ((float*)outp)[off] = resid[off] + v;
                }
            }
        }
    }
}

// ---------------- fused MLP v5: LN2 + fc1 + GELU + fc2 + residual --------------------
// 128 rows/block (512 blocks = ONE occupancy pass at 2 blocks/CU), 4 waves, each wave
// owns TWO 16-row tiles. A-operand in registers (MFMA A-frag layout). Proven r10 v2
// sync structure (Bs1 dbuf + Bs2 single + counted vmcnt, 3 barriers/chunk) with 2x
// MFMA per barrier; each Bs1 fragment read feeds both halves. Yl (wave-private) is
// time-shared between halves (same-wave DS ordering keeps pack(h1) after reads(h0)).
__global__ __launch_bounds__(256, 2) void mlp_kernel(float* out,
                                                     const ushortT* __restrict__ fc1t,
                                                     const ushortT* __restrict__ fc2t,
                                                     const float* __restrict__ fc1b,
                                                     const float* __restrict__ fc2b,
                                                     const float* __restrict__ g,
                                                     const float* __restrict__ b) {
    __shared__ ushortT Bs1[2][64 * 192];      // 48K dbuf
    __shared__ ushortT Bs2[192 * 64];         // 24K
    __shared__ unsigned int Yl[4][16 * 32];   // 8K  -> 80K total, 2 blocks/CU
    int tid = threadIdx.x, lane = tid & 63, wid = tid >> 6;
    int l15 = lane & 15, l4 = lane >> 4;
    size_t bm = (size_t)blockIdx.x * 128;

    // staging source offsets (pre-swizzled global source, linear LDS dest)
    int aoff1[6], aoff2[6];
#pragma unroll
    for (int i = 0; i < 6; ++i) {
        int u = tid + i * 256;
        int r1 = u / 24, rem = u - r1 * 24;   // fc1: 64 rows x 24 granules(16B)
        int kt = rem >> 3, w = rem & 7;
        aoff1[i] = r1 * 192 + kt * 64 + ((w ^ (r1 & 7)) << 3);
        int r2 = u >> 3, wp2 = u & 7;         // fc2: 192 rows x 8 granules(16B)
        aoff2[i] = r2 * 768 + ((wp2 ^ (r2 & 7)) << 3);
    }
    auto STAGE_B1 = [&](int buf, int hc) {
#pragma unroll
        for (int i = 0; i < 6; ++i)
            GLOBAL_LOAD_LDS16(fc1t + hc * 12288 + aoff1[i], &Bs1[buf][(tid + i * 256) * 8]);
    };
    auto STAGE_B2 = [&](int hc) {
#pragma unroll
        for (int i = 0; i < 6; ++i)
            GLOBAL_LOAD_LDS16(fc2t + hc * 64 + aoff2[i], &Bs2[(tid + i * 256) * 8]);
    };

    STAGE_B1(0, 0);   // chunk 0 in flight under the LN prologue

    // ---- LN2 prologue directly into A-fragments (registers), both halves ----
    short8v af[2][6];
#pragma unroll
    for (int hh = 0; hh < 2; ++hh) {
        int row = wid * 32 + hh * 16 + l15;
        const float* xr = out + (bm + row) * 192;
        float v[6][8];
        float s = 0.f, ss = 0.f;
#pragma unroll
        for (int f = 0; f < 6; ++f) {
            int base = (f >> 1) * 64 + (f & 1) * 32 + l4 * 8;
            f32x4 a0 = *(const f32x4*)(xr + base);
            f32x4 a1 = *(const f32x4*)(xr + base + 4);
#pragma unroll
            for (int j = 0; j < 4; ++j) {
                v[f][j] = a0[j]; v[f][4 + j] = a1[j];
                s += a0[j] + a1[j];
                ss += a0[j] * a0[j] + a1[j] * a1[j];
            }
        }
        s += __shfl_xor(s, 16); ss += __shfl_xor(ss, 16);
        s += __shfl_xor(s, 32); ss += __shfl_xor(ss, 32);
        float mean = s * (1.0f / 192.0f);
        float rstd = rsqrtf(ss * (1.0f / 192.0f) - mean * mean + 1e-5f);
#pragma unroll
        for (int f = 0; f < 6; ++f) {
            int base = (f >> 1) * 64 + (f & 1) * 32 + l4 * 8;
#pragma unroll
            for (int j = 0; j < 8; ++j)
                af[hh][f][j] = (short)f2bf((v[f][j] - mean) * rstd * g[base + j] + b[base + j]);
        }
    }

    f32x4 accO[2][12];
#pragma unroll
    for (int hh = 0; hh < 2; ++hh)
#pragma unroll
        for (int nf = 0; nf < 12; ++nf)
#pragma unroll
            for (int r = 0; r < 4; ++r) accO[hh][nf][r] = 0.f;

    for (int hc = 0; hc < 12; ++hc) {
        int cur = hc & 1;
        if (hc < 11) STAGE_B1(cur ^ 1, hc + 1);
        STAGE_B2(hc);
        if (hc < 11) asm volatile("s_waitcnt vmcnt(12)" ::: "memory");  // B1(cur) landed
        else         asm volatile("s_waitcnt vmcnt(6)"  ::: "memory");
        __builtin_amdgcn_s_barrier();
        // GEMM1 both halves: one Bs1 fragment read feeds two MFMAs
        f32x4 ya0[4], ya1[4];
#pragma unroll
        for (int n = 0; n < 4; ++n) {
            float bv = fc1b[hc * 64 + n * 16 + l15];
            ya0[n][0] = bv; ya0[n][1] = bv; ya0[n][2] = bv; ya0[n][3] = bv;
            ya1[n][0] = bv; ya1[n][1] = bv; ya1[n][2] = bv; ya1[n][3] = bv;
        }
        __builtin_amdgcn_s_setprio(1);
#pragma unroll
        for (int kt = 0; kt < 3; ++kt)
#pragma unroll
            for (int ks = 0; ks < 2; ++ks) {
                int wp = ((ks * 4 + l4) ^ (l15 & 7)) << 3;
#pragma unroll
                for (int n = 0; n < 4; ++n) {
                    short8v bf = *(const short8v*)&Bs1[cur][(n * 16 + l15) * 192 + kt * 64 + wp];
                    ya0[n] = __builtin_amdgcn_mfma_f32_16x16x32_bf16(af[0][kt * 2 + ks], bf, ya0[n], 0, 0, 0);
                    ya1[n] = __builtin_amdgcn_mfma_f32_16x16x32_bf16(af[1][kt * 2 + ks], bf, ya1[n], 0, 0, 0);
                }
            }
        __builtin_amdgcn_s_setprio(0);
        // GELU + pack h0 -> Yl (rows 4*l4+r), XOR chunk swizzle (key row&7)
#pragma unroll
        for (int r = 0; r < 4; ++r) {
            int row = 4 * l4 + r;
            int key = row & 7;
#pragma unroll
            for (int gg = 0; gg < 2; ++gg) {
                float y0 = fast_gelu(ya0[gg * 2 + 0][r]);
                float y1 = fast_gelu(ya0[gg * 2 + 1][r]);
                unsigned int pk;
                asm("v_cvt_pk_bf16_f32 %0, %1, %2" : "=v"(pk) : "v"(y0), "v"(y1));
                int ucol = gg * 16 + l15;
                int ch = (ucol >> 2) ^ key;
                Yl[wid][row * 32 + ch * 4 + (ucol & 3)] = pk;
            }
        }
        if (hc < 11) asm volatile("s_waitcnt vmcnt(6)" ::: "memory");   // B2(hc) landed
        else         asm volatile("s_waitcnt vmcnt(0)" ::: "memory");
        __builtin_amdgcn_s_barrier();
        // GEMM2 h0
        __builtin_amdgcn_s_setprio(1);
#pragma unroll
        for (int gg = 0; gg < 2; ++gg) {
            u32x4 pr = *(const u32x4*)&Yl[wid][l15 * 32 + (((gg * 4 + l4) ^ (l15 & 7)) << 2)];
            short8v pa = __builtin_bit_cast(short8v, pr);
#pragma unroll
            for (int nf = 0; nf < 12; ++nf) {
                short8v bf = *(const short8v*)&Bs2[(nf * 16 + l15) * 64 + (((gg * 4 + l4) ^ (l15 & 7)) << 3)];
                accO[0][nf] = __builtin_amdgcn_mfma_f32_16x16x32_bf16(pa, bf, accO[0][nf], 0, 0, 0);
            }
        }
        __builtin_amdgcn_s_setprio(0);
        // GELU + pack h1 -> Yl (same wave-private buffer; same-wave DS order keeps
        // these writes after GEMM2 h0's Yl reads)
#pragma unroll
        for (int r = 0; r < 4; ++r) {
            int row = 4 * l4 + r;
            int key = row & 7;
#pragma unroll
            for (int gg = 0; gg < 2; ++gg) {
                float y0 = fast_gelu(ya1[gg * 2 + 0][r]);
                float y1 = fast_gelu(ya1[gg * 2 + 1][r]);
                unsigned int pk;
                asm("v_cvt_pk_bf16_f32 %0, %1, %2" : "=v"(pk) : "v"(y0), "v"(y1));
                int ucol = gg * 16 + l15;
                int ch = (ucol >> 2) ^ key;
                Yl[wid][row * 32 + ch * 4 + (ucol & 3)] = pk;
            }
        }
        // GEMM2 h1
        __builtin_amdgcn_s_setprio(1);
#pragma unroll
        for (int gg = 0; gg < 2; ++gg) {
            u32x4 pr = *(const u32x4*)&Yl[wid][l15 * 32 + (((gg * 4 + l4) ^ (l15 & 7)) << 2)];
            short8v pa = __builtin_bit_cast(short8v, pr);
#pragma unroll
            for (int nf = 0; nf < 12; ++nf) {
                short8v bf = *(const short8v*)&Bs2[(nf * 16 + l15) * 64 + (((gg * 4 + l4) ^ (l15 & 7)) << 3)];
                accO[1][nf] = __builtin_amdgcn_mfma_f32_16x16x32_bf16(pa, bf, accO[1][nf], 0, 0, 0);
            }
        }
        __builtin_amdgcn_s_setprio(0);
        __builtin_amdgcn_s_barrier();   // Bs1[cur]/Bs2 free for restage next chunk
    }
    // epilogue: out += fc2 bias + acc (residual already in out), both halves
#pragma unroll
    for (int hh = 0; hh < 2; ++hh) {
        size_t row0 = bm + wid * 32 + hh * 16 + l4 * 4;
#pragma unroll
        for (int nf = 0; nf < 12; ++nf) {
            int col = nf * 16 + l15;
            float bv = fc2b[col];
#pragma unroll
            for (int r = 0; r < 4; ++r) {
                size_t off = (row0 + r) * 192 + col;
                out[off] = out[off] + bv + accO[hh][nf][r];
            }
        }
    }
}

// ---------------- MFMA flash attention (r13-exact: no prefetch, per-mf interleave) ---
__global__ __launch_bounds__(256, 4) void attn_mfma_kernel(const ushortT* __restrict__ qkv,
                                                           const float* __restrict__ BTf,
                                                           ushortT* __restrict__ O) {
    __shared__ ushortT Vt[32][264];
    __shared__ unsigned int Ps[4][64][20];
    int wh = blockIdx.x;
    int w = wh / 6, h = wh - w * 6;
    int wi = w >> 4, wj = w & 15;
    int tid = threadIdx.x, lane = tid & 63, wid = tid >> 6;
    int l15 = lane & 15, l4 = lane >> 4;

    {
        int t = tid;
        int pcol = (t & ~31) | (((t & 15) << 1) | ((t >> 4) & 1));
        size_t gr = (size_t)((wi * 16 + (t >> 4)) * 256 + wj * 16 + (t & 15));
        const ushortT* vp = qkv + gr * 576 + 384 + h * 32;
#pragma unroll
        for (int d0 = 0; d0 < 32; d0 += 8) {
            short8v u = *(const short8v*)(vp + d0);
#pragma unroll
            for (int j = 0; j < 8; ++j) Vt[d0 + j][pcol] = (ushortT)u[j];
        }
    }
    short8v qf[4];
    int qbase = wid * 64;
#pragma unroll
    for (int mf = 0; mf < 4; ++mf) {
        int q = qbase + mf * 16 + l15;
        size_t gr = (size_t)((wi * 16 + (q >> 4)) * 256 + wj * 16 + (q & 15));
        qf[mf] = *(const short8v*)(qkv + gr * 576 + h * 32 + l4 * 8);
    }
    __syncthreads();

    float l_run[4][4];
    f32x4 accO[4][2];
#pragma unroll
    for (int mf = 0; mf < 4; ++mf)
#pragma unroll
        for (int r = 0; r < 4; ++r) {
            l_run[mf][r] = 0.f;
            accO[mf][0][r] = 0.f;
            accO[mf][1][r] = 0.f;
        }
    const float* btb = BTf + ((size_t)(h * 8) * 32 + wid * 8) * 256 + lane * 4;

    for (int kc = 0; kc < 8; ++kc) {
        short8v kf[2];
#pragma unroll
        for (int cf = 0; cf < 2; ++cf) {
            int kv = kc * 32 + cf * 16 + l15;
            size_t gr = (size_t)((wi * 16 + (kv >> 4)) * 256 + wj * 16 + (kv & 15));
            kf[cf] = *(const short8v*)(qkv + gr * 576 + 192 + h * 32 + l4 * 8);
        }
        short8v vb[2];
#pragma unroll
        for (int nf = 0; nf < 2; ++nf)
            vb[nf] = *(const short8v*)&Vt[nf * 16 + l15][kc * 32 + l4 * 8];
#pragma unroll
        for (int mf = 0; mf < 4; ++mf) {
            f32x4 s0 = *(const f32x4*)(btb + (size_t)(kc * 32 + mf * 2 + 0) * 256);
            f32x4 s1 = *(const f32x4*)(btb + (size_t)(kc * 32 + mf * 2 + 1) * 256);
            __builtin_amdgcn_s_setprio(1);
            s0 = __builtin_amdgcn_mfma_f32_16x16x32_bf16(qf[mf], kf[0], s0, 0, 0, 0);
            s1 = __builtin_amdgcn_mfma_f32_16x16x32_bf16(qf[mf], kf[1], s1, 0, 0, 0);
            __builtin_amdgcn_s_setprio(0);
#pragma unroll
            for (int r = 0; r < 4; ++r) {
                float p0 = exp2f(s0[r]);
                float p1 = exp2f(s1[r]);
                l_run[mf][r] += p0 + p1;
                unsigned int pk;
                asm("v_cvt_pk_bf16_f32 %0, %1, %2" : "=v"(pk) : "v"(p0), "v"(p1));
                Ps[wid][mf * 16 + 4 * l4 + r][l15] = pk;
            }
            u32x4 pr = *(const u32x4*)&Ps[wid][mf * 16 + l15][l4 * 4];
            short8v pa = __builtin_bit_cast(short8v, pr);
            __builtin_amdgcn_s_setprio(1);
            accO[mf][0] = __builtin_amdgcn_mfma_f32_16x16x32_bf16(pa, vb[0], accO[mf][0], 0, 0, 0);
            accO[mf][1] = __builtin_amdgcn_mfma_f32_16x16x32_bf16(pa, vb[1], accO[mf][1], 0, 0, 0);
            __builtin_amdgcn_s_setprio(0);
        }
    }
#pragma unroll
    for (int mf = 0; mf < 4; ++mf)
#pragma unroll
        for (int r = 0; r < 4; ++r) {
            float l = l_run[mf][r];
            l += __shfl_xor(l, 1);
            l += __shfl_xor(l, 2);
            l += __shfl_xor(l, 4);
            l += __shfl_xor(l, 8);
            l_run[mf][r] = 1.0f / l;
        }
#pragma unroll
    for (int mf = 0; mf < 4; ++mf) {
        int q0 = qbase + mf * 16 + 4 * l4;
#pragma unroll
        for (int r = 0; r < 4; ++r) {
            int q = q0 + r;
            size_t gr = (size_t)((wi * 16 + (q >> 4)) * 256 + wj * 16 + (q & 15));
            ushortT* op = O + gr * 192 + h * 32 + l15;
            float inv = l_run[mf][r];
            op[0]  = f2bf(accO[mf][0][r] * inv);
            op[16] = f2bf(accO[mf][1][r] * inv);
        }
    }
}

// ---------------- launch --------------------------------------------------------------
extern "C" void kernel_launch(void* const* d_in, const int* in_sizes, int n_in,
                              void* d_out, int out_size, void* d_ws, size_t ws_size,
                              hipStream_t stream) {
    const float* x        = (const float*)d_in[0];
    const float* gamma1   = (const float*)d_in[1];
    const float* beta1    = (const float*)d_in[2];
    const float* qkv_w    = (const float*)d_in[3];
    const float* qkv_b    = (const float*)d_in[4];
    const float* proj_w   = (const float*)d_in[5];
    const float* proj_b   = (const float*)d_in[6];
    const float* pos_proj_w = (const float*)d_in[7];
    const float* pos_proj_b = (const float*)d_in[8];
    const float* ln1_g    = (const float*)d_in[9];
    const float* ln1_b    = (const float*)d_in[10];
    const float* pos1_w   = (const float*)d_in[11];
    const float* pos1_b   = (const float*)d_in[12];
    const float* ln2_g    = (const float*)d_in[13];
    const float* ln2_b    = (const float*)d_in[14];
    const float* pos2_w   = (const float*)d_in[15];
    const float* pos2_b   = (const float*)d_in[16];
    const float* ln3_g    = (const float*)d_in[17];
    const float* ln3_b    = (const float*)d_in[18];
    const float* pos3_w   = (const float*)d_in[19];
    const float* pos3_b   = (const float*)d_in[20];
    const float* gamma2   = (const float*)d_in[21];
    const float* beta2    = (const float*)d_in[22];
    const float* fc1_w    = (const float*)d_in[23];
    const float* fc1_b    = (const float*)d_in[24];
    const float* fc2_w    = (const float*)d_in[25];
    const float* fc2_b    = (const float*)d_in[26];
    float* out = (float*)d_out;

    char* ws = (char*)d_ws;
    ushortT* qkv = (ushortT*)(ws + 0);               // 75.5MB
    ushortT* xn   = (ushortT*)(ws + 100663296);      // 25.2MB (xn -> Obuf)
    ushortT* Obuf = xn;
    ushortT* qkv_wt  = (ushortT*)(ws + 125829120);
    ushortT* proj_wt = (ushortT*)(ws + 126050304);
    ushortT* fc1_wt  = (ushortT*)(ws + 126124032);
    ushortT* fc2_wt  = (ushortT*)(ws + 126418944);
    float*   BTf     = (float*)(ws + 126713856);

    // 0. prep (transposes + bias table) + LN1, merged into one dispatch
    prep_ln_kernel<<<18352, 256, 0, stream>>>(
        qkv_w, proj_w, fc1_w, fc2_w, qkv_wt, proj_wt, fc1_wt, fc2_wt,
        pos_proj_w, pos_proj_b, ln1_g, ln1_b, pos1_w, pos1_b,
        ln2_g, ln2_b, pos2_w, pos2_b, ln3_g, ln3_b, pos3_w, pos3_b, BTf,
        x, gamma1, beta1, xn);
    // 1. QKV GEMM (q-cols pre-scaled)
    mfma_gemm<0, 9, 192><<<(M_ROWS / 128) * (QKV_N / 64), 256, 0, stream>>>(
        xn, qkv_wt, qkv_b, nullptr, qkv, QKV_N);
    // 2. attention -> Obuf (overwrites xn)
    attn_mfma_kernel<<<1536, 256, 0, stream>>>(qkv, BTf, Obuf);
    // 3. proj GEMM + residual -> out (f32)
    mfma_gemm<2, 3, 192><<<(M_ROWS / 128) * (DIM / 64), 256, 0, stream>>>(
        Obuf, proj_wt, proj_b, x, out, DIM);
    // 4. fused MLP v5: LN2 + fc1 + GELU + fc2 + residual, 128 rows/block, in-place
    mlp_kernel<<<M_ROWS / 128, 256, 0, stream>>>(
        out, fc1_wt, fc2_wt, fc1_b, fc2_b, gamma2, beta2);
}